// Round 1
// baseline (1629.362 us; speedup 1.0000x reference)
//
#include <hip/hip_runtime.h>

#define NFEAT 256
#define NHID 128
#define NCLASS 40
#define NNODES 50000
#define NEDGES 800000
#define BN_EPS 1e-5f

// ---------------- init: zero stats, out=b1, agg1=b0 ----------------
__global__ void k_init(float* __restrict__ stats, float* __restrict__ out,
                       float* __restrict__ agg1,
                       const float* __restrict__ b0, const float* __restrict__ b1) {
    int i = blockIdx.x * blockDim.x + threadIdx.x;
    if (i < 512) stats[i] = 0.f;                       // sums + sumsq
    if (i < NNODES * NCLASS) out[i] = b1[i % NCLASS];  // out init with bias
    if (i < NNODES * NHID) agg1[i] = b0[i & (NHID - 1)];
}

// ---------------- GEMM1: h1 = x @ W0  [50000x256]x[256x128] ----------------
__launch_bounds__(256)
__global__ void k_gemm1(const float* __restrict__ x, const float* __restrict__ W0,
                        float* __restrict__ h1) {
    __shared__ float xs[64 * 64];          // 64 rows x 64 k  (16 KB)
    const int t = threadIdx.x;
    const int block_row = blockIdx.x * 64;
    const int cg = t & 31, rg = t >> 5;
    const int c0 = cg * 4, r0 = rg * 8;
    float acc[8][4] = {};

    for (int kc = 0; kc < 4; ++kc) {
        const int k0 = kc * 64;
        // stage 64x64 x-tile (coalesced float4)
        {
            const int kk = (t & 15) * 4;
            const int rbase = t >> 4;      // 0..15
            #pragma unroll
            for (int p = 0; p < 4; ++p) {
                const int row = p * 16 + rbase;
                const int g = block_row + row;
                float4 v = make_float4(0.f, 0.f, 0.f, 0.f);
                if (g < NNODES)
                    v = *(const float4*)&x[(long)g * NFEAT + k0 + kk];
                *(float4*)&xs[row * 64 + kk] = v;
            }
        }
        __syncthreads();
        for (int k4 = 0; k4 < 16; ++k4) {
            const int k = k4 * 4;
            const float4 w0v = *(const float4*)&W0[(k0 + k + 0) * NHID + c0];
            const float4 w1v = *(const float4*)&W0[(k0 + k + 1) * NHID + c0];
            const float4 w2v = *(const float4*)&W0[(k0 + k + 2) * NHID + c0];
            const float4 w3v = *(const float4*)&W0[(k0 + k + 3) * NHID + c0];
            #pragma unroll
            for (int r = 0; r < 8; ++r) {
                const float4 a = *(const float4*)&xs[(r0 + r) * 64 + k];
                acc[r][0] += a.x * w0v.x + a.y * w1v.x + a.z * w2v.x + a.w * w3v.x;
                acc[r][1] += a.x * w0v.y + a.y * w1v.y + a.z * w2v.y + a.w * w3v.y;
                acc[r][2] += a.x * w0v.z + a.y * w1v.z + a.z * w2v.z + a.w * w3v.z;
                acc[r][3] += a.x * w0v.w + a.y * w1v.w + a.z * w2v.w + a.w * w3v.w;
            }
        }
        __syncthreads();
    }
    #pragma unroll
    for (int r = 0; r < 8; ++r) {
        const int g = block_row + r0 + r;
        if (g < NNODES)
            *(float4*)&h1[(long)g * NHID + c0] =
                make_float4(acc[r][0], acc[r][1], acc[r][2], acc[r][3]);
    }
}

// ---------------- scatter1: agg1[dst] += h1[src], 128 feats ----------------
__global__ void k_scatter1(const int* __restrict__ ei, const float* __restrict__ h1,
                           float* __restrict__ agg1) {
    const int tid = blockIdx.x * blockDim.x + threadIdx.x;
    if (tid >= NEDGES * 32) return;
    const int e = tid >> 5;
    const int f = (tid & 31) * 4;
    const int src = ei[e];
    const int dst = ei[NEDGES + e];
    const float4 v = *(const float4*)&h1[(long)src * NHID + f];
    float* p = &agg1[(long)dst * NHID + f];
    atomicAdd(p + 0, v.x);
    atomicAdd(p + 1, v.y);
    atomicAdd(p + 2, v.z);
    atomicAdd(p + 3, v.w);
}

// ---------------- BN stats: per-column sum & sumsq ----------------
__global__ void k_bnstats(const float* __restrict__ agg1,
                          float* __restrict__ sums, float* __restrict__ sumsq) {
    __shared__ float sd[256], sd2[256];
    const int t = threadIdx.x;
    const int c = t & 127;
    float s = 0.f, s2 = 0.f;
    for (int r = blockIdx.x * 2 + (t >> 7); r < NNODES; r += gridDim.x * 2) {
        const float v = agg1[(long)r * NHID + c];
        s += v; s2 += v * v;
    }
    sd[t] = s; sd2[t] = s2;
    __syncthreads();
    if (t < 128) {
        atomicAdd(&sums[c], sd[t] + sd[t + 128]);
        atomicAdd(&sumsq[c], sd2[t] + sd2[t + 128]);
    }
}

__global__ void k_bnfinal(const float* __restrict__ sums, const float* __restrict__ sumsq,
                          const float* __restrict__ gamma, const float* __restrict__ beta,
                          float* __restrict__ scale, float* __restrict__ shift) {
    const int t = threadIdx.x;
    if (t < NHID) {
        const float mu = sums[t] * (1.f / NNODES);
        float var = sumsq[t] * (1.f / NNODES) - mu * mu;
        var = fmaxf(var, 0.f);
        const float sc = gamma[t] * rsqrtf(var + BN_EPS);
        scale[t] = sc;
        shift[t] = beta[t] - mu * sc;
    }
}

// ---------------- GEMM2 fused BN+ReLU: h2 = relu(bn(agg1)) @ W1 ----------------
__launch_bounds__(256)
__global__ void k_gemm2(const float* __restrict__ agg1, const float* __restrict__ W1,
                        const float* __restrict__ scale, const float* __restrict__ shift,
                        float* __restrict__ h2) {
    __shared__ float xs[64 * 132];   // padded stride 132 (16B-aligned, conflict-free)
    __shared__ float wt[40 * 132];   // W1 transposed [j][c]
    const int t = threadIdx.x;
    const int base = blockIdx.x * 64;

    for (int idx = t; idx < NHID * NCLASS; idx += 256) {
        const int c = idx / NCLASS, j = idx % NCLASS;
        wt[j * 132 + c] = W1[idx];
    }
    {
        const int cc = (t & 31) * 4;
        const float4 sc = *(const float4*)&scale[cc];
        const float4 sh = *(const float4*)&shift[cc];
        const int rb = t >> 5;  // 0..7
        #pragma unroll
        for (int p = 0; p < 8; ++p) {
            const int row = p * 8 + rb;
            const int g = base + row;
            float4 v = make_float4(0.f, 0.f, 0.f, 0.f);
            if (g < NNODES) {
                const float4 a = *(const float4*)&agg1[(long)g * NHID + cc];
                v.x = fmaxf(a.x * sc.x + sh.x, 0.f);
                v.y = fmaxf(a.y * sc.y + sh.y, 0.f);
                v.z = fmaxf(a.z * sc.z + sh.z, 0.f);
                v.w = fmaxf(a.w * sc.w + sh.w, 0.f);
            }
            *(float4*)&xs[row * 132 + cc] = v;
        }
    }
    __syncthreads();

    const int node = t >> 2;
    const int j0 = (t & 3) * 10;
    float acc[10] = {};
    for (int c4 = 0; c4 < 32; ++c4) {
        const int c = c4 * 4;
        const float4 a = *(const float4*)&xs[node * 132 + c];
        #pragma unroll
        for (int jj = 0; jj < 10; ++jj) {
            const float4 wv = *(const float4*)&wt[(j0 + jj) * 132 + c];
            acc[jj] += a.x * wv.x + a.y * wv.y + a.z * wv.z + a.w * wv.w;
        }
    }
    const int g = base + node;
    if (g < NNODES) {
        #pragma unroll
        for (int jj = 0; jj < 10; ++jj)
            h2[(long)g * NCLASS + j0 + jj] = acc[jj];
    }
}

// ---------------- scatter2: out[dst] += h2[src], 40 feats ----------------
__global__ void k_scatter2(const int* __restrict__ ei, const float* __restrict__ h2,
                           float* __restrict__ out) {
    const unsigned tid = blockIdx.x * blockDim.x + threadIdx.x;
    if (tid >= (unsigned)NEDGES * NCLASS) return;
    const unsigned e = tid / NCLASS;
    const unsigned f = tid - e * NCLASS;
    const int src = ei[e];
    const int dst = ei[NEDGES + e];
    atomicAdd(&out[(long)dst * NCLASS + f], h2[(long)src * NCLASS + f]);
}

extern "C" void kernel_launch(void* const* d_in, const int* in_sizes, int n_in,
                              void* d_out, int out_size, void* d_ws, size_t ws_size,
                              hipStream_t stream) {
    const float* x      = (const float*)d_in[0];
    const int*   ei     = (const int*)d_in[1];
    const float* W0     = (const float*)d_in[2];
    const float* b0     = (const float*)d_in[3];
    const float* gamma0 = (const float*)d_in[4];
    const float* beta0  = (const float*)d_in[5];
    const float* W1     = (const float*)d_in[6];
    const float* b1     = (const float*)d_in[7];
    float* out = (float*)d_out;

    char* ws = (char*)d_ws;
    float* sums  = (float*)ws;        // 128
    float* sumsq = sums + 128;        // 128
    float* scale = sums + 256;        // 128
    float* shift = sums + 384;        // 128
    float* h1   = (float*)(ws + 2048);            // 50000*128 f32
    float* agg1 = h1 + (size_t)NNODES * NHID;     // 50000*128 f32
    float* h2   = h1;                              // h1 dead after scatter1

    k_init<<<25000, 256, 0, stream>>>(sums, out, agg1, b0, b1);
    k_gemm1<<<(NNODES + 63) / 64, 256, 0, stream>>>(x, W0, h1);
    k_scatter1<<<(NEDGES * 32 + 255) / 256, 256, 0, stream>>>(ei, h1, agg1);
    k_bnstats<<<256, 256, 0, stream>>>(agg1, sums, sumsq);
    k_bnfinal<<<1, 128, 0, stream>>>(sums, sumsq, gamma0, beta0, scale, shift);
    k_gemm2<<<(NNODES + 63) / 64, 256, 0, stream>>>(agg1, W1, scale, shift, h2);
    k_scatter2<<<(NEDGES * NCLASS + 255) / 256, 256, 0, stream>>>(ei, h2, out);
}

// Round 2
// 340.264 us; speedup vs baseline: 4.7885x; 4.7885x over previous
//
#include <hip/hip_runtime.h>

#define NFEAT 256
#define NHID 128
#define NCLASS 40
#define NNODES 50000
#define NEDGES 800000
#define BN_EPS 1e-5f
#define CHUNK 1024
#define NCHUNK 49   // ceil(50000/1024)

// ---------------- zero: deg + bn stats ----------------
__global__ void k_zero(int* __restrict__ deg, float* __restrict__ stats) {
    int i = blockIdx.x * blockDim.x + threadIdx.x;
    if (i < NNODES) deg[i] = 0;
    if (i < 256) stats[i] = 0.f;
}

// ---------------- CSR build ----------------
__global__ void k_hist(const int* __restrict__ ei, int* __restrict__ deg) {
    int e = blockIdx.x * blockDim.x + threadIdx.x;
    if (e < NEDGES) atomicAdd(&deg[ei[NEDGES + e]], 1);
}

__global__ void k_chunksum(const int* __restrict__ deg, int* __restrict__ chunksum) {
    __shared__ int sd[256];
    const int b = blockIdx.x, t = threadIdx.x;
    const int base = b * CHUNK + t * 4;
    int s = 0;
    #pragma unroll
    for (int k = 0; k < 4; ++k) { int i = base + k; if (i < NNODES) s += deg[i]; }
    sd[t] = s; __syncthreads();
    for (int off = 128; off > 0; off >>= 1) {
        if (t < off) sd[t] += sd[t + off];
        __syncthreads();
    }
    if (t == 0) chunksum[b] = sd[0];
}

__global__ void k_chunkoff(const int* __restrict__ chunksum, int* __restrict__ chunkoff) {
    if (threadIdx.x == 0) {
        int run = 0;
        for (int i = 0; i < NCHUNK; ++i) { chunkoff[i] = run; run += chunksum[i]; }
    }
}

__global__ void k_rowptr(const int* __restrict__ deg, const int* __restrict__ chunkoff,
                         int* __restrict__ rowptr) {
    __shared__ int ts[256];
    const int b = blockIdx.x, t = threadIdx.x;
    const int base = b * CHUNK + t * 4;
    int d[4]; int s = 0;
    #pragma unroll
    for (int k = 0; k < 4; ++k) { int i = base + k; d[k] = (i < NNODES) ? deg[i] : 0; s += d[k]; }
    ts[t] = s; __syncthreads();
    for (int off = 1; off < 256; off <<= 1) {
        int v = (t >= off) ? ts[t - off] : 0;
        __syncthreads();
        ts[t] += v;
        __syncthreads();
    }
    int excl = ts[t] - s + chunkoff[b];
    #pragma unroll
    for (int k = 0; k < 4; ++k) { int i = base + k; if (i < NNODES) rowptr[i] = excl; excl += d[k]; }
    if (b == NCHUNK - 1 && t == 255) rowptr[NNODES] = excl;  // = NEDGES
}

__global__ void k_cursor(const int* __restrict__ rowptr, int* __restrict__ cursor) {
    int i = blockIdx.x * blockDim.x + threadIdx.x;
    if (i < NNODES) cursor[i] = rowptr[i];
}

__global__ void k_fill(const int* __restrict__ ei, int* __restrict__ cursor,
                       int* __restrict__ esrc) {
    int e = blockIdx.x * blockDim.x + threadIdx.x;
    if (e >= NEDGES) return;
    const int src = ei[e];
    const int dst = ei[NEDGES + e];
    const int pos = atomicAdd(&cursor[dst], 1);
    esrc[pos] = src;
}

// ---------------- GEMM1: h1 = x @ W0  [50000x256]x[256x128] ----------------
__launch_bounds__(256)
__global__ void k_gemm1(const float* __restrict__ x, const float* __restrict__ W0,
                        float* __restrict__ h1) {
    __shared__ float xs[64 * 64];
    const int t = threadIdx.x;
    const int block_row = blockIdx.x * 64;
    const int cg = t & 31, rg = t >> 5;
    const int c0 = cg * 4, r0 = rg * 8;
    float acc[8][4] = {};

    for (int kc = 0; kc < 4; ++kc) {
        const int k0 = kc * 64;
        {
            const int kk = (t & 15) * 4;
            const int rbase = t >> 4;
            #pragma unroll
            for (int p = 0; p < 4; ++p) {
                const int row = p * 16 + rbase;
                const int g = block_row + row;
                float4 v = make_float4(0.f, 0.f, 0.f, 0.f);
                if (g < NNODES)
                    v = *(const float4*)&x[(long)g * NFEAT + k0 + kk];
                *(float4*)&xs[row * 64 + kk] = v;
            }
        }
        __syncthreads();
        for (int k4 = 0; k4 < 16; ++k4) {
            const int k = k4 * 4;
            const float4 w0v = *(const float4*)&W0[(k0 + k + 0) * NHID + c0];
            const float4 w1v = *(const float4*)&W0[(k0 + k + 1) * NHID + c0];
            const float4 w2v = *(const float4*)&W0[(k0 + k + 2) * NHID + c0];
            const float4 w3v = *(const float4*)&W0[(k0 + k + 3) * NHID + c0];
            #pragma unroll
            for (int r = 0; r < 8; ++r) {
                const float4 a = *(const float4*)&xs[(r0 + r) * 64 + k];
                acc[r][0] += a.x * w0v.x + a.y * w1v.x + a.z * w2v.x + a.w * w3v.x;
                acc[r][1] += a.x * w0v.y + a.y * w1v.y + a.z * w2v.y + a.w * w3v.y;
                acc[r][2] += a.x * w0v.z + a.y * w1v.z + a.z * w2v.z + a.w * w3v.z;
                acc[r][3] += a.x * w0v.w + a.y * w1v.w + a.z * w2v.w + a.w * w3v.w;
            }
        }
        __syncthreads();
    }
    #pragma unroll
    for (int r = 0; r < 8; ++r) {
        const int g = block_row + r0 + r;
        if (g < NNODES)
            *(float4*)&h1[(long)g * NHID + c0] =
                make_float4(acc[r][0], acc[r][1], acc[r][2], acc[r][3]);
    }
}

// ---------------- gather1: agg1[n] = b0 + sum h1[src], one wave per node ----------------
__launch_bounds__(256)
__global__ void k_gather1(const int* __restrict__ rowptr, const int* __restrict__ esrc,
                          const float* __restrict__ h1, const float* __restrict__ b0,
                          float* __restrict__ agg1) {
    const int w = (blockIdx.x * blockDim.x + threadIdx.x) >> 6;
    const int lane = threadIdx.x & 63;
    if (w >= NNODES) return;
    const int beg = rowptr[w], end = rowptr[w + 1];
    const int f = lane * 2;
    float2 acc = *(const float2*)&b0[f];
    int i = beg;
    for (; i + 3 < end; i += 4) {
        const int s0 = esrc[i], s1 = esrc[i + 1], s2 = esrc[i + 2], s3 = esrc[i + 3];
        const float2 v0 = *(const float2*)&h1[(long)s0 * NHID + f];
        const float2 v1 = *(const float2*)&h1[(long)s1 * NHID + f];
        const float2 v2 = *(const float2*)&h1[(long)s2 * NHID + f];
        const float2 v3 = *(const float2*)&h1[(long)s3 * NHID + f];
        acc.x += (v0.x + v1.x) + (v2.x + v3.x);
        acc.y += (v0.y + v1.y) + (v2.y + v3.y);
    }
    for (; i < end; ++i) {
        const float2 v = *(const float2*)&h1[(long)esrc[i] * NHID + f];
        acc.x += v.x; acc.y += v.y;
    }
    *(float2*)&agg1[(long)w * NHID + f] = acc;
}

// ---------------- BN stats ----------------
__global__ void k_bnstats(const float* __restrict__ agg1,
                          float* __restrict__ sums, float* __restrict__ sumsq) {
    __shared__ float sd[256], sd2[256];
    const int t = threadIdx.x;
    const int c = t & 127;
    float s = 0.f, s2 = 0.f;
    for (int r = blockIdx.x * 2 + (t >> 7); r < NNODES; r += gridDim.x * 2) {
        const float v = agg1[(long)r * NHID + c];
        s += v; s2 += v * v;
    }
    sd[t] = s; sd2[t] = s2;
    __syncthreads();
    if (t < 128) {
        atomicAdd(&sums[c], sd[t] + sd[t + 128]);
        atomicAdd(&sumsq[c], sd2[t] + sd2[t + 128]);
    }
}

__global__ void k_bnfinal(const float* __restrict__ sums, const float* __restrict__ sumsq,
                          const float* __restrict__ gamma, const float* __restrict__ beta,
                          float* __restrict__ scale, float* __restrict__ shift) {
    const int t = threadIdx.x;
    if (t < NHID) {
        const float mu = sums[t] * (1.f / NNODES);
        float var = sumsq[t] * (1.f / NNODES) - mu * mu;
        var = fmaxf(var, 0.f);
        const float sc = gamma[t] * rsqrtf(var + BN_EPS);
        scale[t] = sc;
        shift[t] = beta[t] - mu * sc;
    }
}

// ---------------- GEMM2 fused BN+ReLU ----------------
__launch_bounds__(256)
__global__ void k_gemm2(const float* __restrict__ agg1, const float* __restrict__ W1,
                        const float* __restrict__ scale, const float* __restrict__ shift,
                        float* __restrict__ h2) {
    __shared__ float xs[64 * 132];
    __shared__ float wt[40 * 132];
    const int t = threadIdx.x;
    const int base = blockIdx.x * 64;

    for (int idx = t; idx < NHID * NCLASS; idx += 256) {
        const int c = idx / NCLASS, j = idx % NCLASS;
        wt[j * 132 + c] = W1[idx];
    }
    {
        const int cc = (t & 31) * 4;
        const float4 sc = *(const float4*)&scale[cc];
        const float4 sh = *(const float4*)&shift[cc];
        const int rb = t >> 5;
        #pragma unroll
        for (int p = 0; p < 8; ++p) {
            const int row = p * 8 + rb;
            const int g = base + row;
            float4 v = make_float4(0.f, 0.f, 0.f, 0.f);
            if (g < NNODES) {
                const float4 a = *(const float4*)&agg1[(long)g * NHID + cc];
                v.x = fmaxf(a.x * sc.x + sh.x, 0.f);
                v.y = fmaxf(a.y * sc.y + sh.y, 0.f);
                v.z = fmaxf(a.z * sc.z + sh.z, 0.f);
                v.w = fmaxf(a.w * sc.w + sh.w, 0.f);
            }
            *(float4*)&xs[row * 132 + cc] = v;
        }
    }
    __syncthreads();

    const int node = t >> 2;
    const int j0 = (t & 3) * 10;
    float acc[10] = {};
    for (int c4 = 0; c4 < 32; ++c4) {
        const int c = c4 * 4;
        const float4 a = *(const float4*)&xs[node * 132 + c];
        #pragma unroll
        for (int jj = 0; jj < 10; ++jj) {
            const float4 wv = *(const float4*)&wt[(j0 + jj) * 132 + c];
            acc[jj] += a.x * wv.x + a.y * wv.y + a.z * wv.z + a.w * wv.w;
        }
    }
    const int g = base + node;
    if (g < NNODES) {
        #pragma unroll
        for (int jj = 0; jj < 10; ++jj)
            h2[(long)g * NCLASS + j0 + jj] = acc[jj];
    }
}

// ---------------- gather2: out[n] = b1 + sum h2[src], one wave per node ----------------
__launch_bounds__(256)
__global__ void k_gather2(const int* __restrict__ rowptr, const int* __restrict__ esrc,
                          const float* __restrict__ h2, const float* __restrict__ b1,
                          float* __restrict__ out) {
    const int w = (blockIdx.x * blockDim.x + threadIdx.x) >> 6;
    const int lane = threadIdx.x & 63;
    if (w >= NNODES || lane >= NCLASS) return;
    const int beg = rowptr[w], end = rowptr[w + 1];
    float acc = b1[lane];
    int i = beg;
    for (; i + 3 < end; i += 4) {
        acc += (h2[(long)esrc[i] * NCLASS + lane] + h2[(long)esrc[i + 1] * NCLASS + lane])
             + (h2[(long)esrc[i + 2] * NCLASS + lane] + h2[(long)esrc[i + 3] * NCLASS + lane]);
    }
    for (; i < end; ++i) acc += h2[(long)esrc[i] * NCLASS + lane];
    out[(long)w * NCLASS + lane] = acc;
}

extern "C" void kernel_launch(void* const* d_in, const int* in_sizes, int n_in,
                              void* d_out, int out_size, void* d_ws, size_t ws_size,
                              hipStream_t stream) {
    const float* x      = (const float*)d_in[0];
    const int*   ei     = (const int*)d_in[1];
    const float* W0     = (const float*)d_in[2];
    const float* b0     = (const float*)d_in[3];
    const float* gamma0 = (const float*)d_in[4];
    const float* beta0  = (const float*)d_in[5];
    const float* W1     = (const float*)d_in[6];
    const float* b1     = (const float*)d_in[7];
    float* out = (float*)d_out;

    char* ws = (char*)d_ws;
    float* sums  = (float*)ws;        // 128
    float* sumsq = sums + 128;
    float* scale = sums + 256;
    float* shift = sums + 384;
    int* wsI      = (int*)(ws + 4096);
    int* deg      = wsI;              // 50000
    int* cursor   = wsI + 50048;      // 50000
    int* rowptr   = wsI + 100096;     // 50001
    int* chunksum = wsI + 150160;     // 49
    int* chunkoff = wsI + 150224;     // 49
    int* esrc     = wsI + 150288;     // 800000
    float* h1   = (float*)(ws + 3805696);          // 50000*128
    float* agg1 = h1 + (size_t)NNODES * NHID;      // 50000*128
    float* h2   = h1;                               // h1 dead after gather1

    k_zero<<<196, 256, 0, stream>>>(deg, sums);
    k_hist<<<(NEDGES + 255) / 256, 256, 0, stream>>>(ei, deg);
    k_chunksum<<<NCHUNK, 256, 0, stream>>>(deg, chunksum);
    k_chunkoff<<<1, 64, 0, stream>>>(chunksum, chunkoff);
    k_rowptr<<<NCHUNK, 256, 0, stream>>>(deg, chunkoff, rowptr);
    k_cursor<<<196, 256, 0, stream>>>(rowptr, cursor);
    k_fill<<<(NEDGES + 255) / 256, 256, 0, stream>>>(ei, cursor, esrc);
    k_gemm1<<<(NNODES + 63) / 64, 256, 0, stream>>>(x, W0, h1);
    k_gather1<<<(NNODES * 64 + 255) / 256, 256, 0, stream>>>(rowptr, esrc, h1, b0, agg1);
    k_bnstats<<<256, 256, 0, stream>>>(agg1, sums, sumsq);
    k_bnfinal<<<1, 128, 0, stream>>>(sums, sumsq, gamma0, beta0, scale, shift);
    k_gemm2<<<(NNODES + 63) / 64, 256, 0, stream>>>(agg1, W1, scale, shift, h2);
    k_gather2<<<(NNODES * 64 + 255) / 256, 256, 0, stream>>>(rowptr, esrc, h2, b1, out);
}

// Round 3
// 262.832 us; speedup vs baseline: 6.1993x; 1.2946x over previous
//
#include <hip/hip_runtime.h>

#define NFEAT 256
#define NHID 128
#define NCLASS 40
#define NNODES 50000
#define NEDGES 800000
#define BN_EPS 1e-5f
#define CHUNK 1024
#define NCHUNK 49   // ceil(50000/1024)

typedef __attribute__((ext_vector_type(4))) float f32x4;
typedef __attribute__((ext_vector_type(8))) short bf16x8;

__device__ inline ushort f2bf(float f) {          // RNE f32 -> bf16
    uint u = __float_as_uint(f);
    u += 0x7FFF + ((u >> 16) & 1);
    return (ushort)(u >> 16);
}
__device__ inline float bflo(uint v) { return __uint_as_float(v << 16); }
__device__ inline float bfhi(uint v) { return __uint_as_float(v & 0xFFFF0000u); }

// ---------------- zero deg ----------------
__global__ void k_zero(int* __restrict__ deg) {
    int i = blockIdx.x * blockDim.x + threadIdx.x;
    if (i < NNODES) deg[i] = 0;
}

// ---------------- CSR build ----------------
__global__ void k_hist(const int* __restrict__ ei, int* __restrict__ deg) {
    int e = blockIdx.x * blockDim.x + threadIdx.x;
    if (e < NEDGES) atomicAdd(&deg[ei[NEDGES + e]], 1);
}

__global__ void k_chunksum(const int* __restrict__ deg, int* __restrict__ chunksum) {
    __shared__ int sd[256];
    const int b = blockIdx.x, t = threadIdx.x;
    const int base = b * CHUNK + t * 4;
    int s = 0;
    #pragma unroll
    for (int k = 0; k < 4; ++k) { int i = base + k; if (i < NNODES) s += deg[i]; }
    sd[t] = s; __syncthreads();
    for (int off = 128; off > 0; off >>= 1) {
        if (t < off) sd[t] += sd[t + off];
        __syncthreads();
    }
    if (t == 0) chunksum[b] = sd[0];
}

__global__ void k_chunkoff(const int* __restrict__ chunksum, int* __restrict__ chunkoff,
                           float* __restrict__ stats) {
    const int t = threadIdx.x;
    if (t < 256) stats[t] = 0.f;  // sums + sumsq
    if (t == 0) {
        int run = 0;
        for (int i = 0; i < NCHUNK; ++i) { chunkoff[i] = run; run += chunksum[i]; }
    }
}

__global__ void k_rowptr(const int* __restrict__ deg, const int* __restrict__ chunkoff,
                         int* __restrict__ rowptr, int* __restrict__ cursor) {
    __shared__ int ts[256];
    const int b = blockIdx.x, t = threadIdx.x;
    const int base = b * CHUNK + t * 4;
    int d[4]; int s = 0;
    #pragma unroll
    for (int k = 0; k < 4; ++k) { int i = base + k; d[k] = (i < NNODES) ? deg[i] : 0; s += d[k]; }
    ts[t] = s; __syncthreads();
    for (int off = 1; off < 256; off <<= 1) {
        int v = (t >= off) ? ts[t - off] : 0;
        __syncthreads();
        ts[t] += v;
        __syncthreads();
    }
    int excl = ts[t] - s + chunkoff[b];
    #pragma unroll
    for (int k = 0; k < 4; ++k) {
        int i = base + k;
        if (i < NNODES) { rowptr[i] = excl; cursor[i] = excl; }
        excl += d[k];
    }
    if (b == NCHUNK - 1 && t == 255) rowptr[NNODES] = excl;  // = NEDGES
}

__global__ void k_fill(const int* __restrict__ ei, int* __restrict__ cursor,
                       int* __restrict__ esrc) {
    int e = blockIdx.x * blockDim.x + threadIdx.x;
    if (e >= NEDGES) return;
    const int src = ei[e];
    const int dst = ei[NEDGES + e];
    const int pos = atomicAdd(&cursor[dst], 1);
    esrc[pos] = src;
}

// ---------------- W0 [256][128] f32 -> W0T [128][256] bf16 ----------------
__global__ void k_w0t(const float* __restrict__ W0, ushort* __restrict__ W0T) {
    __shared__ float tile[128][17];
    const int t = threadIdx.x;
    const int k0 = blockIdx.x * 16;
    const int n = t & 127;
    const int kh = t >> 7;   // 0..1
    #pragma unroll
    for (int p = 0; p < 8; ++p) {
        const int kl = kh * 8 + p;
        tile[n][kl] = W0[(k0 + kl) * NHID + n];
    }
    __syncthreads();
    if (t < 128) {
        uint w[8];
        #pragma unroll
        for (int p = 0; p < 8; ++p)
            w[p] = (uint)f2bf(tile[t][2 * p]) | ((uint)f2bf(tile[t][2 * p + 1]) << 16);
        uint4 a = make_uint4(w[0], w[1], w[2], w[3]);
        uint4 b = make_uint4(w[4], w[5], w[6], w[7]);
        *(uint4*)&W0T[t * 256 + k0] = a;
        *(uint4*)&W0T[t * 256 + k0 + 8] = b;
    }
}

// ---------------- GEMM1 (MFMA bf16): h1 = x @ W0, h1 stored bf16 ----------------
// block = 64 nodes, 4 waves x 16 nodes; K=256 in 8 steps of 32; N=128 full.
__launch_bounds__(256)
__global__ void k_gemm1(const float* __restrict__ x, const ushort* __restrict__ W0T,
                        ushort* __restrict__ h1) {
    __shared__ __align__(16) ushort xs[2][64 * 40];   // padded stride 40 bf16 (80 B)
    const int t = threadIdx.x;
    const int lane = t & 63;
    const int wave = t >> 6;
    const int m_blk = blockIdx.x * 64;

    const int srow = t >> 2;            // staging row 0..63
    const int scol = (t & 3) * 8;       // staging k-offset {0,8,16,24}
    const bool sok = (m_blk + srow) < NNODES;
    const float* xg = &x[(long)(m_blk + srow) * NFEAT + scol];

    const int wn = lane & 15;           // W0T row within fragment
    const int wk = (lane >> 4) * 8;     // k-offset within fragment
    const int ridx = (wave * 16 + (lane & 15)) * 40 + wk;  // LDS read index (ushorts)

    f32x4 acc[8];
    #pragma unroll
    for (int i = 0; i < 8; ++i) acc[i] = (f32x4){0.f, 0.f, 0.f, 0.f};

    // prologue: stage kc=0
    {
        float4 a = make_float4(0.f,0.f,0.f,0.f), b = a;
        if (sok) { a = *(const float4*)(xg); b = *(const float4*)(xg + 4); }
        bf16x8 v;
        v[0]=(short)f2bf(a.x); v[1]=(short)f2bf(a.y); v[2]=(short)f2bf(a.z); v[3]=(short)f2bf(a.w);
        v[4]=(short)f2bf(b.x); v[5]=(short)f2bf(b.y); v[6]=(short)f2bf(b.z); v[7]=(short)f2bf(b.w);
        *(bf16x8*)&xs[0][srow * 40 + scol] = v;
    }

    #pragma unroll
    for (int kc = 0; kc < 8; ++kc) {
        float4 a = make_float4(0.f,0.f,0.f,0.f), b = a;
        if (kc < 7 && sok) {
            a = *(const float4*)(xg + (kc + 1) * 32);
            b = *(const float4*)(xg + (kc + 1) * 32 + 4);
        }
        __syncthreads();
        const bf16x8 xf = *(const bf16x8*)&xs[kc & 1][ridx];
        #pragma unroll
        for (int fi = 0; fi < 8; ++fi) {
            const bf16x8 wf = *(const bf16x8*)&W0T[(fi * 16 + wn) * 256 + kc * 32 + wk];
            acc[fi] = __builtin_amdgcn_mfma_f32_16x16x32_bf16(wf, xf, acc[fi], 0, 0, 0);
        }
        if (kc < 7) {
            bf16x8 v;
            v[0]=(short)f2bf(a.x); v[1]=(short)f2bf(a.y); v[2]=(short)f2bf(a.z); v[3]=(short)f2bf(a.w);
            v[4]=(short)f2bf(b.x); v[5]=(short)f2bf(b.y); v[6]=(short)f2bf(b.z); v[7]=(short)f2bf(b.w);
            *(bf16x8*)&xs[(kc + 1) & 1][srow * 40 + scol] = v;
        }
    }

    // epilogue: D[row=n][col=m]; lane&15 = node, (lane>>4)*4+reg = n (4 consecutive)
    const int m = m_blk + wave * 16 + (lane & 15);
    if (m < NNODES) {
        const int nq = (lane >> 4) * 4;
        #pragma unroll
        for (int fi = 0; fi < 8; ++fi) {
            uint lo = (uint)f2bf(acc[fi][0]) | ((uint)f2bf(acc[fi][1]) << 16);
            uint hi = (uint)f2bf(acc[fi][2]) | ((uint)f2bf(acc[fi][3]) << 16);
            *(uint2*)&h1[(long)m * NHID + fi * 16 + nq] = make_uint2(lo, hi);
        }
    }
}

// ---------------- gather1: agg1[n] = b0 + sum h1[src] (bf16 in, f32 acc/out) ----------------
__launch_bounds__(256)
__global__ void k_gather1(const int* __restrict__ rowptr, const int* __restrict__ esrc,
                          const ushort* __restrict__ h1, const float* __restrict__ b0,
                          float* __restrict__ agg1) {
    const int w = (blockIdx.x * blockDim.x + threadIdx.x) >> 6;
    const int lane = threadIdx.x & 63;
    if (w >= NNODES) return;
    const int beg = rowptr[w], end = rowptr[w + 1];
    const int f = lane * 2;
    float2 acc = *(const float2*)&b0[f];
    int i = beg;
    for (; i + 3 < end; i += 4) {
        const uint v0 = *(const uint*)&h1[(long)esrc[i]     * NHID + f];
        const uint v1 = *(const uint*)&h1[(long)esrc[i + 1] * NHID + f];
        const uint v2 = *(const uint*)&h1[(long)esrc[i + 2] * NHID + f];
        const uint v3 = *(const uint*)&h1[(long)esrc[i + 3] * NHID + f];
        acc.x += (bflo(v0) + bflo(v1)) + (bflo(v2) + bflo(v3));
        acc.y += (bfhi(v0) + bfhi(v1)) + (bfhi(v2) + bfhi(v3));
    }
    for (; i < end; ++i) {
        const uint v = *(const uint*)&h1[(long)esrc[i] * NHID + f];
        acc.x += bflo(v); acc.y += bfhi(v);
    }
    *(float2*)&agg1[(long)w * NHID + f] = acc;
}

// ---------------- BN stats ----------------
__global__ void k_bnstats(const float* __restrict__ agg1,
                          float* __restrict__ sums, float* __restrict__ sumsq) {
    __shared__ float sd[256], sd2[256];
    const int t = threadIdx.x;
    const int c = t & 127;
    float s = 0.f, s2 = 0.f;
    for (int r = blockIdx.x * 2 + (t >> 7); r < NNODES; r += gridDim.x * 2) {
        const float v = agg1[(long)r * NHID + c];
        s += v; s2 += v * v;
    }
    sd[t] = s; sd2[t] = s2;
    __syncthreads();
    if (t < 128) {
        atomicAdd(&sums[c], sd[t] + sd[t + 128]);
        atomicAdd(&sumsq[c], sd2[t] + sd2[t + 128]);
    }
}

__global__ void k_bnfinal(const float* __restrict__ sums, const float* __restrict__ sumsq,
                          const float* __restrict__ gamma, const float* __restrict__ beta,
                          float* __restrict__ scale, float* __restrict__ shift) {
    const int t = threadIdx.x;
    if (t < NHID) {
        const float mu = sums[t] * (1.f / NNODES);
        float var = sumsq[t] * (1.f / NNODES) - mu * mu;
        var = fmaxf(var, 0.f);
        const float sc = gamma[t] * rsqrtf(var + BN_EPS);
        scale[t] = sc;
        shift[t] = beta[t] - mu * sc;
    }
}

// ---------------- GEMM2 fused BN+ReLU: h2(bf16) = relu(bn(agg1)) @ W1 ----------------
__launch_bounds__(256)
__global__ void k_gemm2(const float* __restrict__ agg1, const float* __restrict__ W1,
                        const float* __restrict__ scale, const float* __restrict__ shift,
                        ushort* __restrict__ h2) {
    __shared__ float xs[64 * 132];
    __shared__ float wt[40 * 132];
    const int t = threadIdx.x;
    const int base = blockIdx.x * 64;

    for (int idx = t; idx < NHID * NCLASS; idx += 256) {
        const int c = idx / NCLASS, j = idx % NCLASS;
        wt[j * 132 + c] = W1[idx];
    }
    {
        const int cc = (t & 31) * 4;
        const float4 sc = *(const float4*)&scale[cc];
        const float4 sh = *(const float4*)&shift[cc];
        const int rb = t >> 5;
        #pragma unroll
        for (int p = 0; p < 8; ++p) {
            const int row = p * 8 + rb;
            const int g = base + row;
            float4 v = make_float4(0.f, 0.f, 0.f, 0.f);
            if (g < NNODES) {
                const float4 a = *(const float4*)&agg1[(long)g * NHID + cc];
                v.x = fmaxf(a.x * sc.x + sh.x, 0.f);
                v.y = fmaxf(a.y * sc.y + sh.y, 0.f);
                v.z = fmaxf(a.z * sc.z + sh.z, 0.f);
                v.w = fmaxf(a.w * sc.w + sh.w, 0.f);
            }
            *(float4*)&xs[row * 132 + cc] = v;
        }
    }
    __syncthreads();

    const int node = t >> 2;
    const int j0 = (t & 3) * 10;
    float acc[10] = {};
    for (int c4 = 0; c4 < 32; ++c4) {
        const int c = c4 * 4;
        const float4 a = *(const float4*)&xs[node * 132 + c];
        #pragma unroll
        for (int jj = 0; jj < 10; ++jj) {
            const float4 wv = *(const float4*)&wt[(j0 + jj) * 132 + c];
            acc[jj] += a.x * wv.x + a.y * wv.y + a.z * wv.z + a.w * wv.w;
        }
    }
    const int g = base + node;
    if (g < NNODES) {
        #pragma unroll
        for (int p = 0; p < 5; ++p) {
            uint u = (uint)f2bf(acc[2 * p]) | ((uint)f2bf(acc[2 * p + 1]) << 16);
            *(uint*)&h2[(long)g * NCLASS + j0 + 2 * p] = u;
        }
    }
}

// ---------------- gather2: out[n] = b1 + sum h2[src] (bf16 in, f32 out) ----------------
__launch_bounds__(256)
__global__ void k_gather2(const int* __restrict__ rowptr, const int* __restrict__ esrc,
                          const ushort* __restrict__ h2, const float* __restrict__ b1,
                          float* __restrict__ out) {
    const int w = (blockIdx.x * blockDim.x + threadIdx.x) >> 6;
    const int lane = threadIdx.x & 63;
    if (w >= NNODES || lane >= 20) return;
    const int beg = rowptr[w], end = rowptr[w + 1];
    float2 acc = make_float2(b1[2 * lane], b1[2 * lane + 1]);
    int i = beg;
    for (; i + 3 < end; i += 4) {
        const uint v0 = *(const uint*)&h2[(long)esrc[i]     * NCLASS + 2 * lane];
        const uint v1 = *(const uint*)&h2[(long)esrc[i + 1] * NCLASS + 2 * lane];
        const uint v2 = *(const uint*)&h2[(long)esrc[i + 2] * NCLASS + 2 * lane];
        const uint v3 = *(const uint*)&h2[(long)esrc[i + 3] * NCLASS + 2 * lane];
        acc.x += (bflo(v0) + bflo(v1)) + (bflo(v2) + bflo(v3));
        acc.y += (bfhi(v0) + bfhi(v1)) + (bfhi(v2) + bfhi(v3));
    }
    for (; i < end; ++i) {
        const uint v = *(const uint*)&h2[(long)esrc[i] * NCLASS + 2 * lane];
        acc.x += bflo(v); acc.y += bfhi(v);
    }
    *(float2*)&out[(long)w * NCLASS + 2 * lane] = acc;
}

extern "C" void kernel_launch(void* const* d_in, const int* in_sizes, int n_in,
                              void* d_out, int out_size, void* d_ws, size_t ws_size,
                              hipStream_t stream) {
    const float* x      = (const float*)d_in[0];
    const int*   ei     = (const int*)d_in[1];
    const float* W0     = (const float*)d_in[2];
    const float* b0     = (const float*)d_in[3];
    const float* gamma0 = (const float*)d_in[4];
    const float* beta0  = (const float*)d_in[5];
    const float* W1     = (const float*)d_in[6];
    const float* b1     = (const float*)d_in[7];
    float* out = (float*)d_out;

    char* ws = (char*)d_ws;
    float* sums  = (float*)ws;        // 128
    float* sumsq = sums + 128;
    float* scale = sums + 256;
    float* shift = sums + 384;
    int* wsI      = (int*)(ws + 4096);
    int* deg      = wsI;              // 50000
    int* cursor   = wsI + 50048;
    int* rowptr   = wsI + 100096;     // 50001
    int* chunksum = wsI + 150160;     // 49
    int* chunkoff = wsI + 150224;     // 49
    int* esrc     = wsI + 150288;     // 800000
    ushort* W0T = (ushort*)(ws + 3807232);              // 128*256 bf16 = 64 KB
    ushort* h1  = (ushort*)(ws + 3872768);              // 50000*128 bf16 = 12.8 MB
    float* agg1 = (float*)(ws + 16672768);              // 50000*128 f32 = 25.6 MB
    ushort* h2  = h1;                                    // h1 dead after gather1

    k_w0t<<<16, 256, 0, stream>>>(W0, W0T);
    k_zero<<<196, 256, 0, stream>>>(deg);
    k_hist<<<(NEDGES + 255) / 256, 256, 0, stream>>>(ei, deg);
    k_chunksum<<<NCHUNK, 256, 0, stream>>>(deg, chunksum);
    k_chunkoff<<<1, 256, 0, stream>>>(chunksum, chunkoff, sums);
    k_rowptr<<<NCHUNK, 256, 0, stream>>>(deg, chunkoff, rowptr, cursor);
    k_fill<<<(NEDGES + 255) / 256, 256, 0, stream>>>(ei, cursor, esrc);
    k_gemm1<<<(NNODES + 63) / 64, 256, 0, stream>>>(x, W0T, h1);
    k_gather1<<<(NNODES * 64 + 255) / 256, 256, 0, stream>>>(rowptr, esrc, h1, b0, agg1);
    k_bnstats<<<256, 256, 0, stream>>>(agg1, sums, sumsq);
    k_bnfinal<<<1, 128, 0, stream>>>(sums, sumsq, gamma0, beta0, scale, shift);
    k_gemm2<<<(NNODES + 63) / 64, 256, 0, stream>>>(agg1, W1, scale, shift, h2);
    k_gather2<<<(NNODES * 64 + 255) / 256, 256, 0, stream>>>(rowptr, esrc, h2, b1, out);
}

// Round 4
// 213.572 us; speedup vs baseline: 7.6291x; 1.2307x over previous
//
#include <hip/hip_runtime.h>

#define NFEAT 256
#define NHID 128
#define NCLASS 40
#define NNODES 50000
#define NEDGES 800000
#define BN_EPS 1e-5f
#define NBK 196          // buckets = dst>>8  (50000/256 -> 196)
#define NBLK 100         // edge blocks of 8000
#define EPB 8000
#define BKCAP 6144       // per-bucket LDS capacity (avg 4082, sigma 64)

typedef __attribute__((ext_vector_type(4))) float f32x4;
typedef __attribute__((ext_vector_type(8))) short bf16x8;

__device__ inline ushort f2bf(float f) {          // RNE f32 -> bf16
    uint u = __float_as_uint(f);
    u += 0x7FFF + ((u >> 16) & 1);
    return (ushort)(u >> 16);
}
__device__ inline float bflo(uint v) { return __uint_as_float(v << 16); }
__device__ inline float bfhi(uint v) { return __uint_as_float(v & 0xFFFF0000u); }

// ---------------- bucket count: bcnt[blk][b] ----------------
__global__ void k_bkcount(const int* __restrict__ ei, int* __restrict__ bcnt) {
    __shared__ int cnt[NBK];
    const int t = threadIdx.x, blk = blockIdx.x;
    if (t < NBK) cnt[t] = 0;
    __syncthreads();
    const int base = blk * EPB;
    for (int i = t; i < EPB; i += 256)
        atomicAdd(&cnt[ei[NEDGES + base + i] >> 8], 1);
    __syncthreads();
    if (t < NBK) bcnt[blk * NBK + t] = cnt[t];
}

// ---------------- scan: bucket starts + per-block offsets; zero stats ----------------
__global__ void k_bkscan(const int* __restrict__ bcnt, int* __restrict__ off,
                         int* __restrict__ bstart, int* __restrict__ rowptr,
                         float* __restrict__ stats) {
    __shared__ int tot[NBK];
    __shared__ int bs[NBK + 1];
    const int t = threadIdx.x;
    if (t < 256) stats[t] = 0.f;
    if (t < NBK) {
        int s = 0;
        for (int blk = 0; blk < NBLK; ++blk) s += bcnt[blk * NBK + t];
        tot[t] = s;
    }
    __syncthreads();
    if (t == 0) {
        int run = 0;
        for (int b = 0; b < NBK; ++b) { bs[b] = run; run += tot[b]; }
        bs[NBK] = run;
        rowptr[NNODES] = NEDGES;
    }
    __syncthreads();
    if (t <= NBK) bstart[t] = bs[t];
    if (t < NBK) {
        int run = bs[t];
        for (int blk = 0; blk < NBLK; ++blk) {
            off[blk * NBK + t] = run;
            run += bcnt[blk * NBK + t];
        }
    }
}

// ---------------- scatter packed (dstLow<<16 | src) into bucket regions ----------------
__global__ void k_bkscatter(const int* __restrict__ ei, const int* __restrict__ off,
                            uint* __restrict__ packed) {
    __shared__ int cur[NBK];
    const int t = threadIdx.x, blk = blockIdx.x;
    if (t < NBK) cur[t] = off[blk * NBK + t];
    __syncthreads();
    const int base = blk * EPB;
    for (int i = t; i < EPB; i += 256) {
        const int src = ei[base + i];
        const int dst = ei[NEDGES + base + i];
        const int pos = atomicAdd(&cur[dst >> 8], 1);
        packed[pos] = (uint)src | ((uint)(dst & 255) << 16);
    }
}

// ---------------- per-bucket LDS counting sort -> esrc + rowptr ----------------
__launch_bounds__(256)
__global__ void k_bksort(const uint* __restrict__ packed, const int* __restrict__ bstart,
                         int* __restrict__ esrc, int* __restrict__ rowptr) {
    __shared__ uint pr[BKCAP];
    __shared__ int cnt[256], sc[256], cur[256];
    const int t = threadIdx.x, b = blockIdx.x;
    const int nb = bstart[b], ne = bstart[b + 1];
    const int n = ne - nb;
    cnt[t] = 0;
    __syncthreads();
    for (int i = t; i < n; i += 256) {
        const uint p = packed[nb + i];
        pr[i] = p;
        atomicAdd(&cnt[p >> 16], 1);
    }
    __syncthreads();
    const int v = cnt[t];
    sc[t] = v;
    __syncthreads();
    for (int o = 1; o < 256; o <<= 1) {
        const int tmp = (t >= o) ? sc[t - o] : 0;
        __syncthreads();
        sc[t] += tmp;
        __syncthreads();
    }
    const int excl = sc[t] - v;
    cur[t] = excl;
    const int node = (b << 8) + t;
    if (node < NNODES) rowptr[node] = nb + excl;
    __syncthreads();
    for (int i = t; i < n; i += 256) {
        const uint p = pr[i];
        const int pos = atomicAdd(&cur[p >> 16], 1);
        esrc[nb + pos] = (int)(p & 0xFFFFu);
    }
}

// ---------------- W0 [256][128] f32 -> W0T [128][256] bf16 ----------------
__global__ void k_w0t(const float* __restrict__ W0, ushort* __restrict__ W0T) {
    __shared__ float tile[128][17];
    const int t = threadIdx.x;
    const int k0 = blockIdx.x * 16;
    const int n = t & 127;
    const int kh = t >> 7;
    #pragma unroll
    for (int p = 0; p < 8; ++p) {
        const int kl = kh * 8 + p;
        tile[n][kl] = W0[(k0 + kl) * NHID + n];
    }
    __syncthreads();
    if (t < 128) {
        uint w[8];
        #pragma unroll
        for (int p = 0; p < 8; ++p)
            w[p] = (uint)f2bf(tile[t][2 * p]) | ((uint)f2bf(tile[t][2 * p + 1]) << 16);
        *(uint4*)&W0T[t * 256 + k0] = make_uint4(w[0], w[1], w[2], w[3]);
        *(uint4*)&W0T[t * 256 + k0 + 8] = make_uint4(w[4], w[5], w[6], w[7]);
    }
}

// ---------------- GEMM1 (MFMA bf16): h1 = x @ W0, h1 stored bf16 ----------------
__launch_bounds__(256)
__global__ void k_gemm1(const float* __restrict__ x, const ushort* __restrict__ W0T,
                        ushort* __restrict__ h1) {
    __shared__ __align__(16) ushort xs[2][64 * 40];
    const int t = threadIdx.x;
    const int lane = t & 63;
    const int wave = t >> 6;
    const int m_blk = blockIdx.x * 64;

    const int srow = t >> 2;
    const int scol = (t & 3) * 8;
    const bool sok = (m_blk + srow) < NNODES;
    const float* xg = &x[(long)(m_blk + srow) * NFEAT + scol];

    const int wn = lane & 15;
    const int wk = (lane >> 4) * 8;
    const int ridx = (wave * 16 + (lane & 15)) * 40 + wk;

    f32x4 acc[8];
    #pragma unroll
    for (int i = 0; i < 8; ++i) acc[i] = (f32x4){0.f, 0.f, 0.f, 0.f};

    {
        float4 a = make_float4(0.f,0.f,0.f,0.f), b = a;
        if (sok) { a = *(const float4*)(xg); b = *(const float4*)(xg + 4); }
        bf16x8 v;
        v[0]=(short)f2bf(a.x); v[1]=(short)f2bf(a.y); v[2]=(short)f2bf(a.z); v[3]=(short)f2bf(a.w);
        v[4]=(short)f2bf(b.x); v[5]=(short)f2bf(b.y); v[6]=(short)f2bf(b.z); v[7]=(short)f2bf(b.w);
        *(bf16x8*)&xs[0][srow * 40 + scol] = v;
    }

    #pragma unroll
    for (int kc = 0; kc < 8; ++kc) {
        float4 a = make_float4(0.f,0.f,0.f,0.f), b = a;
        if (kc < 7 && sok) {
            a = *(const float4*)(xg + (kc + 1) * 32);
            b = *(const float4*)(xg + (kc + 1) * 32 + 4);
        }
        __syncthreads();
        const bf16x8 xf = *(const bf16x8*)&xs[kc & 1][ridx];
        #pragma unroll
        for (int fi = 0; fi < 8; ++fi) {
            const bf16x8 wf = *(const bf16x8*)&W0T[(fi * 16 + wn) * 256 + kc * 32 + wk];
            acc[fi] = __builtin_amdgcn_mfma_f32_16x16x32_bf16(wf, xf, acc[fi], 0, 0, 0);
        }
        if (kc < 7) {
            bf16x8 v;
            v[0]=(short)f2bf(a.x); v[1]=(short)f2bf(a.y); v[2]=(short)f2bf(a.z); v[3]=(short)f2bf(a.w);
            v[4]=(short)f2bf(b.x); v[5]=(short)f2bf(b.y); v[6]=(short)f2bf(b.z); v[7]=(short)f2bf(b.w);
            *(bf16x8*)&xs[(kc + 1) & 1][srow * 40 + scol] = v;
        }
    }

    const int m = m_blk + wave * 16 + (lane & 15);
    if (m < NNODES) {
        const int nq = (lane >> 4) * 4;
        #pragma unroll
        for (int fi = 0; fi < 8; ++fi) {
            uint lo = (uint)f2bf(acc[fi][0]) | ((uint)f2bf(acc[fi][1]) << 16);
            uint hi = (uint)f2bf(acc[fi][2]) | ((uint)f2bf(acc[fi][3]) << 16);
            *(uint2*)&h1[(long)m * NHID + fi * 16 + nq] = make_uint2(lo, hi);
        }
    }
}

// ---------------- gather1: agg1[n] = b0 + sum h1[src] ----------------
__launch_bounds__(256)
__global__ void k_gather1(const int* __restrict__ rowptr, const int* __restrict__ esrc,
                          const ushort* __restrict__ h1, const float* __restrict__ b0,
                          float* __restrict__ agg1) {
    const int w = (blockIdx.x * blockDim.x + threadIdx.x) >> 6;
    const int lane = threadIdx.x & 63;
    if (w >= NNODES) return;
    const int beg = rowptr[w], end = rowptr[w + 1];
    const int f = lane * 2;
    float2 acc = *(const float2*)&b0[f];
    int i = beg;
    for (; i + 3 < end; i += 4) {
        const uint v0 = *(const uint*)&h1[(long)esrc[i]     * NHID + f];
        const uint v1 = *(const uint*)&h1[(long)esrc[i + 1] * NHID + f];
        const uint v2 = *(const uint*)&h1[(long)esrc[i + 2] * NHID + f];
        const uint v3 = *(const uint*)&h1[(long)esrc[i + 3] * NHID + f];
        acc.x += (bflo(v0) + bflo(v1)) + (bflo(v2) + bflo(v3));
        acc.y += (bfhi(v0) + bfhi(v1)) + (bfhi(v2) + bfhi(v3));
    }
    for (; i < end; ++i) {
        const uint v = *(const uint*)&h1[(long)esrc[i] * NHID + f];
        acc.x += bflo(v); acc.y += bfhi(v);
    }
    *(float2*)&agg1[(long)w * NHID + f] = acc;
}

// ---------------- BN stats (float4) ----------------
__global__ void k_bnstats(const float* __restrict__ agg1,
                          float* __restrict__ sums, float* __restrict__ sumsq) {
    __shared__ float sd[256 * 4], sd2[256 * 4];
    const int t = threadIdx.x;
    const int c4 = (t & 31) * 4;
    const int rr = t >> 5;
    float4 s = make_float4(0.f,0.f,0.f,0.f), s2 = s;
    for (int r = blockIdx.x * 8 + rr; r < NNODES; r += gridDim.x * 8) {
        const float4 v = *(const float4*)&agg1[(long)r * NHID + c4];
        s.x += v.x; s.y += v.y; s.z += v.z; s.w += v.w;
        s2.x += v.x*v.x; s2.y += v.y*v.y; s2.z += v.z*v.z; s2.w += v.w*v.w;
    }
    *(float4*)&sd[t * 4] = s; *(float4*)&sd2[t * 4] = s2;
    __syncthreads();
    if (t < 32) {
        #pragma unroll
        for (int j = 1; j < 8; ++j) {
            const float4 a = *(const float4*)&sd[(j * 32 + t) * 4];
            const float4 a2 = *(const float4*)&sd2[(j * 32 + t) * 4];
            s = *(float4*)&sd[t * 4];  // keep accumulating in regs
            s2 = *(float4*)&sd2[t * 4];
            s.x += a.x; s.y += a.y; s.z += a.z; s.w += a.w;
            s2.x += a2.x; s2.y += a2.y; s2.z += a2.z; s2.w += a2.w;
            *(float4*)&sd[t * 4] = s; *(float4*)&sd2[t * 4] = s2;
        }
        atomicAdd(&sums[c4 + 0], s.x);  atomicAdd(&sums[c4 + 1], s.y);
        atomicAdd(&sums[c4 + 2], s.z);  atomicAdd(&sums[c4 + 3], s.w);
        atomicAdd(&sumsq[c4 + 0], s2.x); atomicAdd(&sumsq[c4 + 1], s2.y);
        atomicAdd(&sumsq[c4 + 2], s2.z); atomicAdd(&sumsq[c4 + 3], s2.w);
    }
}

__global__ void k_bnfinal(const float* __restrict__ sums, const float* __restrict__ sumsq,
                          const float* __restrict__ gamma, const float* __restrict__ beta,
                          float* __restrict__ scale, float* __restrict__ shift) {
    const int t = threadIdx.x;
    if (t < NHID) {
        const float mu = sums[t] * (1.f / NNODES);
        float var = sumsq[t] * (1.f / NNODES) - mu * mu;
        var = fmaxf(var, 0.f);
        const float sc = gamma[t] * rsqrtf(var + BN_EPS);
        scale[t] = sc;
        shift[t] = beta[t] - mu * sc;
    }
}

// ---------------- GEMM2 fused BN+ReLU: h2(bf16) = relu(bn(agg1)) @ W1 ----------------
__launch_bounds__(256)
__global__ void k_gemm2(const float* __restrict__ agg1, const float* __restrict__ W1,
                        const float* __restrict__ scale, const float* __restrict__ shift,
                        ushort* __restrict__ h2) {
    __shared__ float xs[64 * 132];
    __shared__ float wt[40 * 132];
    const int t = threadIdx.x;
    const int base = blockIdx.x * 64;

    for (int idx = t; idx < NHID * NCLASS; idx += 256) {
        const int c = idx / NCLASS, j = idx % NCLASS;
        wt[j * 132 + c] = W1[idx];
    }
    {
        const int cc = (t & 31) * 4;
        const float4 sc = *(const float4*)&scale[cc];
        const float4 sh = *(const float4*)&shift[cc];
        const int rb = t >> 5;
        #pragma unroll
        for (int p = 0; p < 8; ++p) {
            const int row = p * 8 + rb;
            const int g = base + row;
            float4 v = make_float4(0.f, 0.f, 0.f, 0.f);
            if (g < NNODES) {
                const float4 a = *(const float4*)&agg1[(long)g * NHID + cc];
                v.x = fmaxf(a.x * sc.x + sh.x, 0.f);
                v.y = fmaxf(a.y * sc.y + sh.y, 0.f);
                v.z = fmaxf(a.z * sc.z + sh.z, 0.f);
                v.w = fmaxf(a.w * sc.w + sh.w, 0.f);
            }
            *(float4*)&xs[row * 132 + cc] = v;
        }
    }
    __syncthreads();

    const int node = t >> 2;
    const int j0 = (t & 3) * 10;
    float acc[10] = {};
    for (int c4 = 0; c4 < 32; ++c4) {
        const int c = c4 * 4;
        const float4 a = *(const float4*)&xs[node * 132 + c];
        #pragma unroll
        for (int jj = 0; jj < 10; ++jj) {
            const float4 wv = *(const float4*)&wt[(j0 + jj) * 132 + c];
            acc[jj] += a.x * wv.x + a.y * wv.y + a.z * wv.z + a.w * wv.w;
        }
    }
    const int g = base + node;
    if (g < NNODES) {
        #pragma unroll
        for (int p = 0; p < 5; ++p) {
            uint u = (uint)f2bf(acc[2 * p]) | ((uint)f2bf(acc[2 * p + 1]) << 16);
            *(uint*)&h2[(long)g * NCLASS + j0 + 2 * p] = u;
        }
    }
}

// ---------------- gather2: out[n] = b1 + sum h2[src] ----------------
__launch_bounds__(256)
__global__ void k_gather2(const int* __restrict__ rowptr, const int* __restrict__ esrc,
                          const ushort* __restrict__ h2, const float* __restrict__ b1,
                          float* __restrict__ out) {
    const int w = (blockIdx.x * blockDim.x + threadIdx.x) >> 6;
    const int lane = threadIdx.x & 63;
    if (w >= NNODES || lane >= 20) return;
    const int beg = rowptr[w], end = rowptr[w + 1];
    float2 acc = make_float2(b1[2 * lane], b1[2 * lane + 1]);
    int i = beg;
    for (; i + 3 < end; i += 4) {
        const uint v0 = *(const uint*)&h2[(long)esrc[i]     * NCLASS + 2 * lane];
        const uint v1 = *(const uint*)&h2[(long)esrc[i + 1] * NCLASS + 2 * lane];
        const uint v2 = *(const uint*)&h2[(long)esrc[i + 2] * NCLASS + 2 * lane];
        const uint v3 = *(const uint*)&h2[(long)esrc[i + 3] * NCLASS + 2 * lane];
        acc.x += (bflo(v0) + bflo(v1)) + (bflo(v2) + bflo(v3));
        acc.y += (bfhi(v0) + bfhi(v1)) + (bfhi(v2) + bfhi(v3));
    }
    for (; i < end; ++i) {
        const uint v = *(const uint*)&h2[(long)esrc[i] * NCLASS + 2 * lane];
        acc.x += bflo(v); acc.y += bfhi(v);
    }
    *(float2*)&out[(long)w * NCLASS + 2 * lane] = acc;
}

extern "C" void kernel_launch(void* const* d_in, const int* in_sizes, int n_in,
                              void* d_out, int out_size, void* d_ws, size_t ws_size,
                              hipStream_t stream) {
    const float* x      = (const float*)d_in[0];
    const int*   ei     = (const int*)d_in[1];
    const float* W0     = (const float*)d_in[2];
    const float* b0     = (const float*)d_in[3];
    const float* gamma0 = (const float*)d_in[4];
    const float* beta0  = (const float*)d_in[5];
    const float* W1     = (const float*)d_in[6];
    const float* b1     = (const float*)d_in[7];
    float* out = (float*)d_out;

    char* ws = (char*)d_ws;
    float* sums  = (float*)ws;        // 128
    float* sumsq = sums + 128;
    float* scale = sums + 256;
    float* shift = sums + 384;
    int* wsI      = (int*)(ws + 4096);
    int* rowptr   = wsI;                       // 50001 (pad 50048)
    int* esrc     = wsI + 50048;               // 800000
    int* bcnt     = wsI + 850048;              // 19600 (pad 19648)
    int* off      = wsI + 869696;              // 19600 (pad 19648)
    int* bstart   = wsI + 889344;              // 197 (pad 256)
    ushort* W0T = (ushort*)(ws + 3563520);     // 64 KB
    ushort* h1  = (ushort*)(ws + 3629056);     // 50000*128 bf16 = 12.8 MB
    float* agg1 = (float*)(ws + 16429056);     // 50000*128 f32 = 25.6 MB
    uint* packed = (uint*)agg1;                // 3.2 MB, dead before gather1
    ushort* h2  = h1;                          // h1 dead after gather1

    k_w0t<<<16, 256, 0, stream>>>(W0, W0T);
    k_bkcount<<<NBLK, 256, 0, stream>>>(ei, bcnt);
    k_bkscan<<<1, 256, 0, stream>>>(bcnt, off, bstart, rowptr, sums);
    k_bkscatter<<<NBLK, 256, 0, stream>>>(ei, off, packed);
    k_bksort<<<NBK, 256, 0, stream>>>(packed, bstart, esrc, rowptr);
    k_gemm1<<<(NNODES + 63) / 64, 256, 0, stream>>>(x, W0T, h1);
    k_gather1<<<(NNODES * 64 + 255) / 256, 256, 0, stream>>>(rowptr, esrc, h1, b0, agg1);
    k_bnstats<<<256, 256, 0, stream>>>(agg1, sums, sumsq);
    k_bnfinal<<<1, 128, 0, stream>>>(sums, sumsq, gamma0, beta0, scale, shift);
    k_gemm2<<<(NNODES + 63) / 64, 256, 0, stream>>>(agg1, W1, scale, shift, h2);
    k_gather2<<<(NNODES * 64 + 255) / 256, 256, 0, stream>>>(rowptr, esrc, h2, b1, out);
}